// Round 7
// baseline (429.253 us; speedup 1.0000x reference)
//
#include <hip/hip_runtime.h>
#include <hip/hip_bf16.h>

#define BATCH 4096
#define TT 60
#define FF 158
#define HH 32
#define GG 96   // 3*H

typedef float f4 __attribute__((ext_vector_type(4), aligned(4)));
typedef float f2 __attribute__((ext_vector_type(2), aligned(4)));

__device__ __forceinline__ float fexp(float x) {
    return __builtin_amdgcn_exp2f(x * 1.442695040888963f);
}
__device__ __forceinline__ float fsigmoid(float x) {
    return __builtin_amdgcn_rcpf(1.0f + fexp(-x));
}
__device__ __forceinline__ float ftanh(float x) {
    float e = fexp(2.0f * x);
    return (e - 1.0f) * __builtin_amdgcn_rcpf(e + 1.0f);
}

// ---------------------------------------------------------------------------
// K1: gs[tc][b][g] = sum_f x[b][t0+tc][f] * w_ih[g][f]
// 256 thr = 4 waves; block tile 128 rows x 96 cols; thread tile 8r x 6c.
// Split-K: w staged k-major in ws[80][97] (31KB), two halves (k<80, k>=80),
// re-staged mid-kernel. x tiles wave-private xs[4][8][32] (4KB), register-
// prefetched one 8k-tile ahead -> no barriers inside the K loop.
// LDS total 35,136 B -> 4 blocks/CU (16 waves/CU).
// ---------------------------------------------------------------------------
__global__ __launch_bounds__(256, 4) void k1_gemm(
    const float* __restrict__ x, const float* __restrict__ w_ih,
    float* __restrict__ gs, int t0, int Tc)
{
    __shared__ float ws[80][97];     // 31,040 B; k-major; 97: conflict-free
    __shared__ float xs[4][8][32];   //  4,096 B; wave-private tiles

    const int tid  = threadIdx.x;
    const int lane = tid & 63;
    const int wv   = tid >> 6;

    const int tcol = lane & 15;      // 16 col-groups * 6 cols = 96
    const int trow = lane >> 4;      // 4 row-groups * 8 rows  = 32
    const int g0   = tcol * 6;

    // staging assignment: 32 rows x 8 k per wave tile
    const int srow = lane >> 1;      // 0..31
    const int q    = lane & 1;       // k-half of tile
    const int Rs   = blockIdx.x * 128 + wv * 32 + srow;
    const int bs   = Rs / Tc;
    const int ts   = Rs - bs * Tc;
    const float* xrow = x + ((size_t)bs * TT + (size_t)(t0 + ts)) * FF + q * 4;

    // ---- stage ws half0 (k in [0,80)): coalesced global, bank-stride-1 writes
    for (int i = tid; i < GG * 80; i += 256) {
        int g = i / 80;
        int k = i - g * 80;
        ws[k][g] = w_ih[g * FF + k];
    }
    // ---- x tile 0
    {
        f4 p0 = *(const f4*)xrow;
        xs[wv][q * 4 + 0][srow] = p0.x;
        xs[wv][q * 4 + 1][srow] = p0.y;
        xs[wv][q * 4 + 2][srow] = p0.z;
        xs[wv][q * 4 + 3][srow] = p0.w;
    }
    __syncthreads();

    float acc[8][6];
    #pragma unroll
    for (int u = 0; u < 8; ++u)
        #pragma unroll
        for (int i = 0; i < 6; ++i) acc[u][i] = 0.0f;

#define K1_INNER(KL) {                                                        \
        const f4 a0 = *(const f4*)&xs[wv][kk][trow * 8];                      \
        const f4 a1 = *(const f4*)&xs[wv][kk][trow * 8 + 4];                  \
        const f2 b01 = *(const f2*)&ws[KL][g0];                               \
        const f2 b23 = *(const f2*)&ws[KL][g0 + 2];                           \
        const f2 b45 = *(const f2*)&ws[KL][g0 + 4];                           \
        const float bv[6] = {b01.x, b01.y, b23.x, b23.y, b45.x, b45.y};       \
        _Pragma("unroll")                                                     \
        for (int i = 0; i < 6; ++i) {                                         \
            acc[0][i] = fmaf(a0.x, bv[i], acc[0][i]);                         \
            acc[1][i] = fmaf(a0.y, bv[i], acc[1][i]);                         \
            acc[2][i] = fmaf(a0.z, bv[i], acc[2][i]);                         \
            acc[3][i] = fmaf(a0.w, bv[i], acc[3][i]);                         \
            acc[4][i] = fmaf(a1.x, bv[i], acc[4][i]);                         \
            acc[5][i] = fmaf(a1.y, bv[i], acc[5][i]);                         \
            acc[6][i] = fmaf(a1.z, bv[i], acc[6][i]);                         \
            acc[7][i] = fmaf(a1.w, bv[i], acc[7][i]);                         \
        }                                                                     \
    }

#define K1_STAGE_F4(P) {                                                      \
        xs[wv][q * 4 + 0][srow] = (P).x;                                      \
        xs[wv][q * 4 + 1][srow] = (P).y;                                      \
        xs[wv][q * 4 + 2][srow] = (P).z;                                      \
        xs[wv][q * 4 + 3][srow] = (P).w;                                      \
    }

    // ---- half0: 10 tiles of 8k (k 0..79)
    for (int s = 0; s < 10; ++s) {
        f4 pfn = *(const f4*)(xrow + (s + 1) * 8);   // prefetch next tile (k<=87)
        const int kb = s * 8;
        #pragma unroll
        for (int kk = 0; kk < 8; ++kk) K1_INNER(kb + kk)
        K1_STAGE_F4(pfn)
    }

    // ---- restage ws for half1 (k in [80,158), 78 wide)
    __syncthreads();   // all waves done reading half0
    for (int i = tid; i < GG * 78; i += 256) {
        int g = i / 78;
        int k = i - g * 78;
        ws[k][g] = w_ih[g * FF + 80 + k];
    }
    __syncthreads();

    // ---- half1: 9 tiles of 8k (k 80..151) + 6-wide tail (k 152..157)
    for (int s = 0; s < 9; ++s) {
        const int k0n = 88 + s * 8;
        f4 pfn; f2 pf2;
        if (s < 8) {
            pfn = *(const f4*)(xrow + k0n);
        } else {
            if (q == 0) pfn = *(const f4*)(xrow + 152);      // k 152..155
            else        pf2 = *(const f2*)(xrow + 152);      // k 156..157
        }
        const int kb = s * 8;
        #pragma unroll
        for (int kk = 0; kk < 8; ++kk) K1_INNER(kb + kk)
        if (s < 8) {
            K1_STAGE_F4(pfn)
        } else {
            if (q == 0) {
                xs[wv][0][srow] = pfn.x;
                xs[wv][1][srow] = pfn.y;
                xs[wv][2][srow] = pfn.z;
                xs[wv][3][srow] = pfn.w;
            } else {
                xs[wv][4][srow] = pf2.x;
                xs[wv][5][srow] = pf2.y;
            }
        }
    }
    #pragma unroll
    for (int kk = 0; kk < 6; ++kk) K1_INNER(72 + kk)

#undef K1_INNER
#undef K1_STAGE_F4

    // ---- epilogue: 8 rows x 6 cols per thread, float2 stores
    #pragma unroll
    for (int u = 0; u < 8; ++u) {
        int R2 = blockIdx.x * 128 + wv * 32 + trow * 8 + u;
        int b2 = R2 / Tc;
        int t2 = R2 - b2 * Tc;
        float* dst = gs + ((size_t)t2 * BATCH + b2) * GG + g0;
        f2 v0 = {acc[u][0], acc[u][1]};
        f2 v1 = {acc[u][2], acc[u][3]};
        f2 v2 = {acc[u][4], acc[u][5]};
        *(f2*)(dst)     = v0;
        *(f2*)(dst + 2) = v1;
        *(f2*)(dst + 4) = v2;
    }
}

// ---------------------------------------------------------------------------
// K2: GRU recurrence, zero barriers (wave-synchronous hs ownership).
// Split gate accumulators (chain depth 16). Static fully-scheduled path for
// Tc==60 (5 pairs x 12 steps, double-buffered 6-step gi register chunks).
// ---------------------------------------------------------------------------
__global__ __launch_bounds__(256, 2) void k2_rec(
    const float* __restrict__ gs, const float* __restrict__ w_hh,
    float* __restrict__ hio, int Tc, int first, int last,
    const float* __restrict__ w1, const float* __restrict__ b1,
    const float* __restrict__ w2, float* __restrict__ out)
{
    __shared__ float hs[8][36];   // padded; wave-private pairs of rows
    __shared__ float ys[8][16];
    const int tid = threadIdx.x;
    const int bl  = tid >> 5;
    const int j   = tid & 31;
    const int b   = blockIdx.x * 8 + bl;

    float wr[32], wz[32], wn[32];
    #pragma unroll
    for (int kk = 0; kk < 8; ++kk) {
        f4 a = *(const f4*)&w_hh[(size_t)(j     ) * HH + kk * 4];
        f4 c = *(const f4*)&w_hh[(size_t)(j + 32) * HH + kk * 4];
        f4 d = *(const f4*)&w_hh[(size_t)(j + 64) * HH + kk * 4];
        wr[kk*4] = a.x; wr[kk*4+1] = a.y; wr[kk*4+2] = a.z; wr[kk*4+3] = a.w;
        wz[kk*4] = c.x; wz[kk*4+1] = c.y; wz[kk*4+2] = c.z; wz[kk*4+3] = c.w;
        wn[kk*4] = d.x; wn[kk*4+1] = d.y; wn[kk*4+2] = d.z; wn[kk*4+3] = d.w;
    }

    float h = first ? 0.0f : hio[(size_t)b * HH + j];
    hs[bl][j] = h;

    const float*  gb = gs + (size_t)b * GG + j;
    const size_t  TS = (size_t)BATCH * GG;

#define K2_STEP(GIR, GIZ, GIN) {                                              \
        float gr0 = 0.f, gz0 = 0.f, gn0 = 0.f;                                \
        float gr1 = 0.f, gz1 = 0.f, gn1 = 0.f;                                \
        _Pragma("unroll")                                                     \
        for (int k = 0; k < 16; k += 4) {                                     \
            f4 hv = *(const f4*)&hs[bl][k];                                   \
            gr0 = fmaf(wr[k  ], hv.x, gr0); gz0 = fmaf(wz[k  ], hv.x, gz0); gn0 = fmaf(wn[k  ], hv.x, gn0); \
            gr0 = fmaf(wr[k+1], hv.y, gr0); gz0 = fmaf(wz[k+1], hv.y, gz0); gn0 = fmaf(wn[k+1], hv.y, gn0); \
            gr0 = fmaf(wr[k+2], hv.z, gr0); gz0 = fmaf(wz[k+2], hv.z, gz0); gn0 = fmaf(wn[k+2], hv.z, gn0); \
            gr0 = fmaf(wr[k+3], hv.w, gr0); gz0 = fmaf(wz[k+3], hv.w, gz0); gn0 = fmaf(wn[k+3], hv.w, gn0); \
        }                                                                     \
        _Pragma("unroll")                                                     \
        for (int k = 16; k < 32; k += 4) {                                    \
            f4 hv = *(const f4*)&hs[bl][k];                                   \
            gr1 = fmaf(wr[k  ], hv.x, gr1); gz1 = fmaf(wz[k  ], hv.x, gz1); gn1 = fmaf(wn[k  ], hv.x, gn1); \
            gr1 = fmaf(wr[k+1], hv.y, gr1); gz1 = fmaf(wz[k+1], hv.y, gz1); gn1 = fmaf(wn[k+1], hv.y, gn1); \
            gr1 = fmaf(wr[k+2], hv.z, gr1); gz1 = fmaf(wz[k+2], hv.z, gz1); gn1 = fmaf(wn[k+2], hv.z, gn1); \
            gr1 = fmaf(wr[k+3], hv.w, gr1); gz1 = fmaf(wz[k+3], hv.w, gz1); gn1 = fmaf(wn[k+3], hv.w, gn1); \
        }                                                                     \
        float r = fsigmoid((GIR) + gr0 + gr1);                                \
        float z = fsigmoid((GIZ) + gz0 + gz1);                                \
        float n = ftanh((GIN) + r * (gn0 + gn1));                             \
        h = (1.0f - z) * n + z * h;                                           \
        hs[bl][j] = h;                                                        \
    }

#define K2_LOAD6(DST, TBASE) {                                                \
        _Pragma("unroll")                                                     \
        for (int u = 0; u < 6; ++u) {                                         \
            DST[u*3+0] = gb[(size_t)((TBASE) + u) * TS];                      \
            DST[u*3+1] = gb[(size_t)((TBASE) + u) * TS + 32];                 \
            DST[u*3+2] = gb[(size_t)((TBASE) + u) * TS + 64];                 \
        }                                                                     \
    }

#define K2_RUN6(SRC) {                                                        \
        _Pragma("unroll")                                                     \
        for (int u = 0; u < 6; ++u) K2_STEP(SRC[u*3], SRC[u*3+1], SRC[u*3+2]) \
    }

    if (Tc == 60) {
        float c0[18], c1[18];
        K2_LOAD6(c0, 0)
        #pragma unroll 1
        for (int p = 0; p < 5; ++p) {
            K2_LOAD6(c1, p * 12 + 6)
            K2_RUN6(c0)
            if (p < 4) K2_LOAD6(c0, p * 12 + 12)
            K2_RUN6(c1)
        }
    } else {
        for (int t = 0; t < Tc; ++t) {
            float gir = gb[(size_t)t * TS];
            float giz = gb[(size_t)t * TS + 32];
            float gin = gb[(size_t)t * TS + 64];
            K2_STEP(gir, giz, gin)
        }
    }
#undef K2_STEP
#undef K2_LOAD6
#undef K2_RUN6

    if (last) {
        // head, wave-synchronous (hs written by this same wave)
        if (j < 16) {
            float y = b1[j];
            #pragma unroll
            for (int k = 0; k < 32; ++k) y = fmaf(w1[j * HH + k], hs[bl][k], y);
            ys[bl][j] = fmaxf(y, 0.0f);
        }
        if (j == 0) {
            float o = 0.0f;
            #pragma unroll
            for (int k = 0; k < 16; ++k) o = fmaf(ys[bl][k], w2[k], o);
            out[b] = o;
        }
    } else {
        hio[(size_t)b * HH + j] = h;
    }
}

// ---------------------------------------------------------------------------
extern "C" void kernel_launch(void* const* d_in, const int* in_sizes, int n_in,
                              void* d_out, int out_size, void* d_ws, size_t ws_size,
                              hipStream_t stream)
{
    const float* x    = (const float*)d_in[0];
    const float* w_ih = (const float*)d_in[1];
    const float* w_hh = (const float*)d_in[2];
    const float* w1   = (const float*)d_in[3];
    const float* b1   = (const float*)d_in[4];
    const float* w2   = (const float*)d_in[5];
    float* out = (float*)d_out;

    // workspace: gi chunk [Tc][B][96] fp32 + h carry [B][32] fp32
    const size_t hbytes = (size_t)BATCH * HH * 4;
    size_t avail = (ws_size > hbytes) ? (ws_size - hbytes) : 0;
    int Tc = (int)(avail / ((size_t)BATCH * GG * 4));
    if (Tc > TT) Tc = TT;
    if (Tc < 1) Tc = 1;

    float* gsbuf = (float*)d_ws;
    float* hio   = (float*)((char*)d_ws + (size_t)BATCH * GG * 4 * (size_t)Tc);

    for (int t0 = 0; t0 < TT; ) {
        int tc = TT - t0; if (tc > Tc) tc = Tc;
        k1_gemm<<<BATCH * tc / 128, 256, 0, stream>>>(x, w_ih, gsbuf, t0, tc);
        int first = (t0 == 0) ? 1 : 0;
        int lastf = (t0 + tc >= TT) ? 1 : 0;
        k2_rec<<<BATCH / 8, 256, 0, stream>>>(gsbuf, w_hh, hio, tc, first, lastf,
                                              w1, b1, w2, out);
        t0 += tc;
    }
}